// Round 15
// baseline (161.617 us; speedup 1.0000x reference)
//
#include <hip/hip_runtime.h>
#include <stdint.h>

typedef unsigned short u16;
typedef __attribute__((ext_vector_type(8))) short bf16x8;
typedef __attribute__((ext_vector_type(4))) float f32x4;
typedef __attribute__((ext_vector_type(8))) u16 u16x8;
typedef __attribute__((ext_vector_type(4))) u16 u16x4;

#define NTOK 8192
#define DDIM 1024
#define HDIM 256
#define NEXP 16
#define MAXT 272            // worst-case 128-row tiles across all experts
#define MAXMT (MAXT * 2)    // 64-row m-tiles
#define MAXSLOT (MAXT * 128)

__device__ __forceinline__ u16 f2bf(float f) {
  uint32_t u = __builtin_bit_cast(uint32_t, f);
  u += 0x7FFFu + ((u >> 16) & 1u);
  return (u16)(u >> 16);
}
__device__ __forceinline__ float bf2f(u16 h) {
  return __builtin_bit_cast(float, (uint32_t)h << 16);
}

// async global->LDS, 16B per lane; dest must be linear in lane order
__device__ __forceinline__ void gll16(const void* g, void* l) {
  __builtin_amdgcn_global_load_lds((const __attribute__((address_space(1))) void*)g,
                                   (__attribute__((address_space(3))) void*)l,
                                   16, 0, 0);
}

// ---------------- fp32 -> bf16 bulk convert (w1 + w2 fused) -----------------
__global__ __launch_bounds__(256) void cvt2_kernel(const float* __restrict__ a,
                                                   const float* __restrict__ b,
                                                   u16* __restrict__ oa,
                                                   u16* __restrict__ ob,
                                                   int nba) {
  const float* in; u16* out;
  int bx = blockIdx.x;
  if (bx < nba) { in = a; out = oa; } else { in = b; out = ob; bx -= nba; }
  size_t i = ((size_t)bx * 256 + threadIdx.x) * 8;
  const float4 p = *(const float4*)(in + i);
  const float4 q = *(const float4*)(in + i + 4);
  u16x8 o;
  o[0] = f2bf(p.x); o[1] = f2bf(p.y); o[2] = f2bf(p.z); o[3] = f2bf(p.w);
  o[4] = f2bf(q.x); o[5] = f2bf(q.y); o[6] = f2bf(q.z); o[7] = f2bf(q.w);
  *(u16x8*)(out + i) = o;
}

__global__ __launch_bounds__(256) void zero_out_kernel(float* __restrict__ p) {
  size_t i = ((size_t)blockIdx.x * 256 + threadIdx.x) * 4;
  *(float4*)(p + i) = (float4){0.f, 0.f, 0.f, 0.f};
}

// ------- router v3: LDS rw (swizzled), 16 threads/token, f64 acc ------------
__global__ __launch_bounds__(256) void router_kernel(const float* __restrict__ x,
                                                     const float* __restrict__ rw,
                                                     int* __restrict__ epack,
                                                     float* __restrict__ ew,
                                                     u16* __restrict__ xbf) {
  __shared__ __align__(16) uint8_t rwlds[65536];
  const int tid = threadIdx.x;

#pragma unroll
  for (int i = 0; i < 16; ++i) {
    int byte = (i * 256 + tid) * 16;
    int sw = byte ^ (((byte >> 8) & 7) << 4);
    *(float4*)(rwlds + sw) = *(const float4*)((const uint8_t*)rw + byte);
  }
  __syncthreads();

  const int lane = tid & 63, wid = tid >> 6;
  const int s = lane & 15;                 // strip: d in [s*64, s*64+64)
  const int tok = blockIdx.x * 16 + wid * 4 + (lane >> 4);
  const float* xrow = x + (size_t)tok * DDIM;
  u16* xbrow = xbf + (size_t)tok * DDIM;

  double acc[NEXP];
#pragma unroll
  for (int e = 0; e < NEXP; ++e) acc[e] = 0.0;

#pragma unroll 4
  for (int g = 0; g < 16; ++g) {
    const int d = s * 64 + g * 4;
    float4 xv = *(const float4*)(xrow + d);
    u16x4 o;
    o[0] = f2bf(xv.x); o[1] = f2bf(xv.y); o[2] = f2bf(xv.z); o[3] = f2bf(xv.w);
    *(u16x4*)(xbrow + d) = o;
    const double x0 = xv.x, x1 = xv.y, x2 = xv.z, x3 = xv.w;
    const int roff = (s * 256 + g * 16) ^ ((s & 7) << 4);
#pragma unroll
    for (int e = 0; e < NEXP; ++e) {
      float4 rv = *(const float4*)(rwlds + e * 4096 + roff);
      acc[e] = fma(x0, (double)rv.x, acc[e]);
      acc[e] = fma(x1, (double)rv.y, acc[e]);
      acc[e] = fma(x2, (double)rv.z, acc[e]);
      acc[e] = fma(x3, (double)rv.w, acc[e]);
    }
  }

#define FOLD(H, M)                                                   \
  _Pragma("unroll") for (int i = 0; i < H; ++i) {                    \
    double send = (lane & M) ? acc[i] : acc[i + H];                  \
    double recv = __shfl_xor(send, M);                               \
    acc[i] = ((lane & M) ? acc[i + H] : acc[i]) + recv;              \
  }
  FOLD(8, 1)
  FOLD(4, 2)
  FOLD(2, 4)
  FOLD(1, 8)
#undef FOLD
  const int e_mine = ((lane & 1) << 3) | ((lane & 2) << 1) |
                     ((lane & 4) >> 1) | ((lane & 8) >> 3);

  double val = acc[0];
  double tv[4]; int tidx[4];
#pragma unroll
  for (int k = 0; k < 4; ++k) {
    double bv = val; int be = e_mine;
#pragma unroll
    for (int m = 1; m < 16; m <<= 1) {
      double ov = __shfl_xor(bv, m);
      int oe = __shfl_xor(be, m);
      if (ov > bv || (ov == bv && oe < be)) { bv = ov; be = oe; }
    }
    tv[k] = bv; tidx[k] = be;
    if (e_mine == be) val = -1.0e300;
  }

  if ((lane & 15) == 0) {
    float m0 = (float)tv[0];
    float w[4]; float sum = 0.f;
#pragma unroll
    for (int k = 0; k < 4; ++k) { w[k] = expf((float)tv[k] - m0); sum += w[k]; }
    epack[tok] = tidx[0] | (tidx[1] << 8) | (tidx[2] << 16) | (tidx[3] << 24);
#pragma unroll
    for (int k = 0; k < 4; ++k) ew[tok * 4 + k] = w[k] / sum;
  }
}

// ------- compact: per-expert deterministic slot assignment (no atomics) -----
__global__ __launch_bounds__(1024) void compact_kernel(const int* __restrict__ epack,
                                                       const float* __restrict__ ew,
                                                       int* __restrict__ texp,
                                                       int* __restrict__ perm,
                                                       float* __restrict__ wsl,
                                                       int* __restrict__ islot) {
  __shared__ int wave_cnt[16][NEXP];
  __shared__ int counts_sm[NEXP];
  __shared__ int wtot[16], wave_off[16];
  const int e = blockIdx.x;
  const int tid = threadIdx.x, lane = tid & 63, w = tid >> 6;

  int ep[8]; unsigned m[8];
#pragma unroll
  for (int j = 0; j < 8; ++j) {
    ep[j] = epack[tid * 8 + j];
    m[j] = (1u << (ep[j] & 255)) | (1u << ((ep[j] >> 8) & 255)) |
           (1u << ((ep[j] >> 16) & 255)) | (1u << ((ep[j] >> 24) & 255));
  }
#pragma unroll
  for (int ee = 0; ee < NEXP; ++ee) {
    int c = 0;
#pragma unroll
    for (int j = 0; j < 8; ++j) c += (m[j] >> ee) & 1u;
#pragma unroll
    for (int off = 32; off > 0; off >>= 1) c += __shfl_xor(c, off);
    if (lane == 0) wave_cnt[w][ee] = c;
  }
  unsigned fm = 0;
#pragma unroll
  for (int j = 0; j < 8; ++j) fm |= ((m[j] >> e) & 1u) << j;
  int s = __popc(fm);
  int incl = s;
#pragma unroll
  for (int d = 1; d < 64; d <<= 1) {
    int t2 = __shfl_up(incl, d);
    if (lane >= d) incl += t2;
  }
  if (lane == 63) wtot[w] = incl;
  __syncthreads();
  if (tid < NEXP) {
    int c = 0;
    for (int w2 = 0; w2 < 16; ++w2) c += wave_cnt[w2][tid];
    counts_sm[tid] = c;
  }
  if (tid == 0) {
    int run = 0;
    for (int w2 = 0; w2 < 16; ++w2) { wave_off[w2] = run; run += wtot[w2]; }
  }
  __syncthreads();
  int base = 0;
  for (int ee = 0; ee < NEXP; ++ee)
    if (ee < e) base += ((counts_sm[ee] + 127) >> 7) << 7;
  int pos = base + wave_off[w] + (incl - s);
#pragma unroll
  for (int j = 0; j < 8; ++j) {
    if ((fm >> j) & 1u) {
      int tok = tid * 8 + j;
      int b0 = ep[j] & 255, b1 = (ep[j] >> 8) & 255, b2_ = (ep[j] >> 16) & 255;
      int k = (b0 == e) ? 0 : ((b1 == e) ? 1 : ((b2_ == e) ? 2 : 3));
      perm[pos] = tok;
      wsl[pos] = ew[tok * 4 + k];
      islot[tok * 4 + k] = pos;
      ++pos;
    }
  }
  int cnt = counts_sm[e];
  int pad = (((cnt + 127) >> 7) << 7) - cnt;
  if (tid < pad) { perm[base + cnt + tid] = 0; wsl[base + cnt + tid] = 0.f; }
  if (e == 0 && tid == 0) {
    int tc = 0;
    for (int ee = 0; ee < NEXP; ++ee) {
      int nt = (counts_sm[ee] + 127) >> 7;
      for (int i = 0; i < nt; ++i) texp[tc++] = ee;
    }
    for (; tc < MAXT; ++tc) texp[tc] = -1;
  }
}

// ---------------- staging (pre-swizzled source -> linear LDS) ---------------
// 128 rows x 64 cols (16 KB): 4 units/thread
__device__ __forceinline__ void stage128(const u16* __restrict__ base, int ld,
                                         int kbase, uint8_t* dst, int tid) {
#pragma unroll
  for (int i = 0; i < 4; ++i) {
    int u = i * 256 + tid;
    int row = u >> 3, g = u & 7;
    gll16(base + (size_t)row * ld + kbase + ((g ^ (row & 7)) << 3), dst + u * 16);
  }
}
// 64 rows x 64 cols (8 KB): 2 units/thread
__device__ __forceinline__ void stage64(const u16* __restrict__ base, int ld,
                                        int kbase, uint8_t* dst, int tid) {
#pragma unroll
  for (int i = 0; i < 2; ++i) {
    int u = i * 256 + tid;
    int row = u >> 3, g = u & 7;
    gll16(base + (size_t)row * ld + kbase + ((g ^ (row & 7)) << 3), dst + u * 16);
  }
}
// gather 64 rows of x by token (8 KB): 2 units/thread
__device__ __forceinline__ void stage_gather64(const u16* __restrict__ xbf,
                                               const int tok[2], int kbase,
                                               uint8_t* dst, int tid) {
#pragma unroll
  for (int i = 0; i < 2; ++i) {
    int u = i * 256 + tid;
    int g = u & 7;
    gll16(xbf + (size_t)tok[i] * DDIM + kbase + ((g ^ ((u >> 3) & 7)) << 3), dst + u * 16);
  }
}

// 64x128 tile, 4 waves (2m x 2n), wave 32x64
__device__ __forceinline__ void mma64(const uint8_t* Ab, const uint8_t* Bb,
                                      f32x4 acc[2][4], int wm, int wn,
                                      int lrow, int lk) {
#pragma unroll
  for (int s = 0; s < 2; ++s) {
    bf16x8 af[2], bfr[4];
#pragma unroll
    for (int f = 0; f < 2; ++f) {
      int ar = wm * 32 + f * 16 + lrow;
      af[f] = *(const bf16x8*)(Ab + ar * 128 + ((((s << 2) | lk) ^ (ar & 7)) << 4));
    }
#pragma unroll
    for (int f = 0; f < 4; ++f) {
      int br = wn * 64 + f * 16 + lrow;
      bfr[f] = *(const bf16x8*)(Bb + br * 128 + ((((s << 2) | lk) ^ (br & 7)) << 4));
    }
#pragma unroll
    for (int i = 0; i < 2; ++i)
#pragma unroll
      for (int j = 0; j < 4; ++j)
        acc[i][j] = __builtin_amdgcn_mfma_f32_16x16x32_bf16(af[i], bfr[j], acc[i][j], 0, 0, 0);
  }
}

// ------- FUSED: per 64-slot tile, H lives in LDS ----------------------------
// Phase 1 (x2 halves): H[64][256] = relu(x[perm] @ W1e^T + b1) -> LDS (swizzled
// chunks identical to stage64's layout). Phase 2: y = relu(H @ W2e^T + b2) with
// A read directly from LDS, B (W2) double-buffered. ybuf out.
__global__ __launch_bounds__(256) void fused_kernel(const u16* __restrict__ xbf,
                                                    const u16* __restrict__ w1bf,
                                                    const u16* __restrict__ w2bf,
                                                    const float* __restrict__ b1,
                                                    const float* __restrict__ b2,
                                                    const int* __restrict__ texp,
                                                    const int* __restrict__ perm,
                                                    u16* __restrict__ ybuf, int NC) {
  __shared__ __align__(16) uint8_t smem[81920];  // H 32KB | staging 48KB
  const int mt = blockIdx.x;
  const int e = texp[mt >> 1];
  if (e < 0) return;
  const int tid = threadIdx.x;
  const int lane = tid & 63, wid = tid >> 6;
  const int wm = wid >> 1, wn = wid & 1;
  const int lrow = lane & 15, lk = lane >> 4;
  uint8_t* stg = smem + 32768;

  int tok[2];
#pragma unroll
  for (int i = 0; i < 2; ++i) tok[i] = perm[mt * 64 + ((i * 256 + tid) >> 3)];

  f32x4 acc[2][4];
#pragma unroll
  for (int i = 0; i < 2; ++i)
#pragma unroll
    for (int j = 0; j < 4; ++j) acc[i][j] = (f32x4){0.f, 0.f, 0.f, 0.f};

  // ---------------- phase 1: two 128-col halves of H ----------------
  for (int half = 0; half < 2; ++half) {
    const u16* Bsrc = w1bf + ((size_t)e * HDIM + half * 128) * DDIM;
    stage_gather64(xbf, tok, 0, stg, tid);
    stage128(Bsrc, DDIM, 0, stg + 8192, tid);
    __syncthreads();
    int cur = 0;
    for (int kt = 0; kt < 16; ++kt) {
      if (kt < 15) {
        stage_gather64(xbf, tok, (kt + 1) * 64, stg + ((cur ^ 1) * 24576), tid);
        stage128(Bsrc, DDIM, (kt + 1) * 64, stg + ((cur ^ 1) * 24576) + 8192, tid);
      }
      mma64(stg + cur * 24576, stg + cur * 24576 + 8192, acc, wm, wn, lrow, lk);
      __syncthreads();
      cur ^= 1;
    }
    // H half -> LDS chunks (half*2+wn), layout identical to stage64 output
#pragma unroll
    for (int j = 0; j < 4; ++j) {
      float bias = b1[e * HDIM + half * 128 + wn * 64 + j * 16 + lrow];
      int g = j * 2 + (lrow >> 3);
#pragma unroll
      for (int i = 0; i < 2; ++i) {
#pragma unroll
        for (int r = 0; r < 4; ++r) {
          int row = wm * 32 + i * 16 + lk * 4 + r;
          float h = fmaxf(acc[i][j][r] + bias, 0.f);
          int addr = (half * 2 + wn) * 8192 + row * 128 +
                     ((g ^ (row & 7)) << 4) + (lrow & 7) * 2;
          *(u16*)(smem + addr) = f2bf(h);
          acc[i][j][r] = 0.f;
        }
      }
    }
  }
  __syncthreads();  // H complete before phase 2 reads

  // ---------------- phase 2: y = relu(H @ W2e^T + b2) ----------------
  const u16* B2 = w2bf + (size_t)e * DDIM * HDIM;
  stage128(B2, HDIM, 0, stg, tid);
  __syncthreads();
  int cur = 0;
  for (int s = 0; s < 32; ++s) {
    const int nb = s >> 2, kt = s & 3;
    if (s < 31) {
      const int nb2 = (s + 1) >> 2, kt2 = (s + 1) & 3;
      stage128(B2 + (size_t)(nb2 * 128) * HDIM, HDIM, kt2 * 64,
               stg + ((cur ^ 1) << 14), tid);
    }
    mma64(smem + kt * 8192, stg + (cur << 14), acc, wm, wn, lrow, lk);
    if (kt == 3) {
#pragma unroll
      for (int j = 0; j < 4; ++j) {
        float bias = b2[e * DDIM + nb * 128 + wn * 64 + j * 16 + lrow];
        int nloc = nb * 128 + wn * 64 + j * 16 + lrow;
#pragma unroll
        for (int i = 0; i < 2; ++i) {
#pragma unroll
          for (int r = 0; r < 4; ++r) {
            int slot = mt * 64 + wm * 32 + i * 16 + lk * 4 + r;
            float h = fmaxf(acc[i][j][r] + bias, 0.f);
            ybuf[(size_t)slot * NC + nloc] = f2bf(h);
            acc[i][j][r] = 0.f;
          }
        }
      }
    }
    __syncthreads();
    cur ^= 1;
  }
}

// ------- GEMM1 (fallback path): Hc = relu(x[perm] @ W1e^T + b1e) ------------
__global__ __launch_bounds__(256) void gemm1_kernel(const u16* __restrict__ xbf,
                                                    const u16* __restrict__ w1bf,
                                                    const float* __restrict__ b1,
                                                    const int* __restrict__ texp,
                                                    const int* __restrict__ perm,
                                                    u16* __restrict__ Hc, int mt0) {
  __shared__ __align__(16) uint8_t smem[2][24576];
  const int mt = mt0 + blockIdx.x;
  const int e = (mt < MAXMT) ? texp[mt >> 1] : -1;
  if (e < 0) return;
  const int n0 = blockIdx.y * 128;
  const int tid = threadIdx.x;
  const int lane = tid & 63, wid = tid >> 6;
  const int wm = wid >> 1, wn = wid & 1;
  const int lrow = lane & 15, lk = lane >> 4;

  int tok[2];
#pragma unroll
  for (int i = 0; i < 2; ++i) tok[i] = perm[mt * 64 + ((i * 256 + tid) >> 3)];
  const u16* Bsrc = w1bf + ((size_t)e * HDIM + n0) * DDIM;

  f32x4 acc[2][4];
#pragma unroll
  for (int i = 0; i < 2; ++i)
#pragma unroll
    for (int j = 0; j < 4; ++j) acc[i][j] = (f32x4){0.f, 0.f, 0.f, 0.f};

  stage_gather64(xbf, tok, 0, smem[0], tid);
  stage128(Bsrc, DDIM, 0, smem[0] + 8192, tid);
  __syncthreads();
  int cur = 0;
  for (int kt = 0; kt < 16; ++kt) {
    if (kt < 15) {
      stage_gather64(xbf, tok, (kt + 1) * 64, smem[cur ^ 1], tid);
      stage128(Bsrc, DDIM, (kt + 1) * 64, smem[cur ^ 1] + 8192, tid);
    }
    mma64(smem[cur], smem[cur] + 8192, acc, wm, wn, lrow, lk);
    __syncthreads();
    cur ^= 1;
  }
#pragma unroll
  for (int j = 0; j < 4; ++j) {
    int n = n0 + wn * 64 + j * 16 + lrow;
    float bias = b1[e * HDIM + n];
#pragma unroll
    for (int i = 0; i < 2; ++i) {
      int rloc = (mt - mt0) * 64 + wm * 32 + i * 16 + lk * 4;
#pragma unroll
      for (int r = 0; r < 4; ++r) {
        float h = fmaxf(acc[i][j][r] + bias, 0.f);
        Hc[((size_t)rloc + r) * HDIM + n] = f2bf(h);
      }
    }
  }
}

// ------- GEMM2 fallback (atomic accumulate) ---------------------------------
__global__ __launch_bounds__(256) void gemm2_fb_kernel(const u16* __restrict__ Hc,
                                                       const u16* __restrict__ w2bf,
                                                       const float* __restrict__ b2,
                                                       const int* __restrict__ texp,
                                                       const int* __restrict__ perm,
                                                       const float* __restrict__ wsl,
                                                       float* __restrict__ out, int mt0) {
  __shared__ __align__(16) uint8_t smem[2][24576];
  const int mt = mt0 + blockIdx.x;
  const int e = (mt < MAXMT) ? texp[mt >> 1] : -1;
  if (e < 0) return;
  const int nl0 = blockIdx.y * 128;
  const int tid = threadIdx.x;
  const int lane = tid & 63, wid = tid >> 6;
  const int wm = wid >> 1, wn = wid & 1;
  const int lrow = lane & 15, lk = lane >> 4;

  const u16* Asrc = Hc + (size_t)(mt - mt0) * 64 * HDIM;
  const u16* Bsrc = w2bf + ((size_t)e * DDIM + nl0) * HDIM;

  f32x4 acc[2][4];
#pragma unroll
  for (int i = 0; i < 2; ++i)
#pragma unroll
    for (int j = 0; j < 4; ++j) acc[i][j] = (f32x4){0.f, 0.f, 0.f, 0.f};

  stage64(Asrc, HDIM, 0, smem[0], tid);
  stage128(Bsrc, HDIM, 0, smem[0] + 8192, tid);
  __syncthreads();
  int cur = 0;
  for (int kt = 0; kt < 4; ++kt) {
    if (kt < 3) {
      stage64(Asrc, HDIM, (kt + 1) * 64, smem[cur ^ 1], tid);
      stage128(Bsrc, HDIM, (kt + 1) * 64, smem[cur ^ 1] + 8192, tid);
    }
    mma64(smem[cur], smem[cur] + 8192, acc, wm, wn, lrow, lk);
    __syncthreads();
    cur ^= 1;
  }
  float bias[4];
#pragma unroll
  for (int j = 0; j < 4; ++j)
    bias[j] = b2[e * DDIM + nl0 + wn * 64 + j * 16 + lrow];
#pragma unroll
  for (int i = 0; i < 2; ++i) {
#pragma unroll
    for (int r = 0; r < 4; ++r) {
      int slot = mt * 64 + wm * 32 + i * 16 + lk * 4 + r;
      int tokn = perm[slot];
      float w = wsl[slot];
#pragma unroll
      for (int j = 0; j < 4; ++j) {
        int n = nl0 + wn * 64 + j * 16 + lrow;
        float h = fmaxf(acc[i][j][r] + bias[j], 0.f);
        atomicAdd(&out[(size_t)tokn * DDIM + n], w * h);
      }
    }
  }
}

// ------- combine: 16 cols/thread --------------------------------------------
__global__ __launch_bounds__(256) void combine_kernel(const u16* __restrict__ ybuf,
                                                      const float* __restrict__ ew,
                                                      const int* __restrict__ islot,
                                                      float* __restrict__ out,
                                                      int n0, int NC, int cshift) {
  int gid = blockIdx.x * 256 + threadIdx.x;
  int t = gid >> cshift;
  int c = (gid & ((1 << cshift) - 1)) << 4;
  const int4 sl = *(const int4*)(islot + t * 4);
  const float4 w = *(const float4*)(ew + t * 4);
  float a[16];
#pragma unroll
  for (int k = 0; k < 16; ++k) a[k] = 0.f;
#define ACCROW(SL, W)                                                      \
  {                                                                        \
    u16x8 y0 = *(const u16x8*)(ybuf + (size_t)(SL)*NC + c);                \
    u16x8 y1 = *(const u16x8*)(ybuf + (size_t)(SL)*NC + c + 8);            \
    _Pragma("unroll") for (int k = 0; k < 8; ++k) {                        \
      a[k] += (W)*bf2f(y0[k]); a[8 + k] += (W)*bf2f(y1[k]);                \
    }                                                                      \
  }
  ACCROW(sl.x, w.x); ACCROW(sl.y, w.y); ACCROW(sl.z, w.z); ACCROW(sl.w, w.w);
#undef ACCROW
  float* o = out + (size_t)t * DDIM + n0 + c;
#pragma unroll
  for (int k = 0; k < 16; k += 4)
    *(float4*)(o + k) = (float4){a[k], a[k + 1], a[k + 2], a[k + 3]};
}

// ---------------------------------------------------------------------------
extern "C" void kernel_launch(void* const* d_in, const int* in_sizes, int n_in,
                              void* d_out, int out_size, void* d_ws, size_t ws_size,
                              hipStream_t stream) {
  const float* x = (const float*)d_in[0];
  const float* route_w = (const float*)d_in[1];
  const float* w1 = (const float*)d_in[2];
  const float* b1 = (const float*)d_in[3];
  const float* w2 = (const float*)d_in[4];
  const float* b2 = (const float*)d_in[5];
  float* out = (float*)d_out;

  uint8_t* ws = (uint8_t*)d_ws;
  const size_t OFF_EPACK = 0;                      // 8192 ints  = 32 KB
  const size_t OFF_EW    = 32768;                  // 32768 f    = 128 KB
  const size_t OFF_ISLOT = 163840;                 // 32768 ints = 128 KB
  const size_t OFF_TEXP  = 294912;                 // 272 ints
  const size_t OFF_PERM  = 296960;                 // 34816 ints
  const size_t OFF_WSL   = 436224;                 // 34816 f
  const size_t OFF_X     = 1048576;                // 16.78 MB bf16 x
  const size_t OFF_W1    = OFF_X + (size_t)NTOK * DDIM * 2;
  const size_t OFF_W2    = OFF_W1 + (size_t)NEXP * HDIM * DDIM * 2;
  const size_t OFF_HC    = OFF_W2 + (size_t)NEXP * DDIM * HDIM * 2;
  const size_t OFF_Y     = OFF_HC + (size_t)MAXSLOT * HDIM * 2;

  int* epack  = (int*)(ws + OFF_EPACK);
  float* ew   = (float*)(ws + OFF_EW);
  int* islot  = (int*)(ws + OFF_ISLOT);
  int* texp   = (int*)(ws + OFF_TEXP);
  int* perm   = (int*)(ws + OFF_PERM);
  float* wsl  = (float*)(ws + OFF_WSL);
  u16* xbf    = (u16*)(ws + OFF_X);
  u16* w1bf   = (u16*)(ws + OFF_W1);
  u16* w2bf   = (u16*)(ws + OFF_W2);
  u16* Hc     = (u16*)(ws + OFF_HC);
  u16* ybuf   = (u16*)(ws + OFF_Y);

  const int nba = (NEXP * HDIM * DDIM) / 2048;
  cvt2_kernel<<<dim3(nba * 2), 256, 0, stream>>>(w1, w2, w1bf, w2bf, nba);
  router_kernel<<<dim3(NTOK / 16), 256, 0, stream>>>(x, route_w, epack, ew, xbf);
  compact_kernel<<<dim3(NEXP), 1024, 0, stream>>>(epack, ew, texp, perm, wsl, islot);

  // main path needs the full 1024-wide ybuf
  const bool full = (ws_size >= OFF_Y + (size_t)MAXSLOT * 1024 * 2);

  if (full) {
    fused_kernel<<<dim3(MAXMT), 256, 0, stream>>>(xbf, w1bf, w2bf, b1, b2,
                                                  texp, perm, ybuf, 1024);
    const int cshift = 6;  // 1024/16 cols-per-thread chunks
    combine_kernel<<<dim3((NTOK << cshift) / 256), 256, 0, stream>>>(
        ybuf, ew, islot, out, 0, 1024, cshift);
  } else {
    long room = (long)ws_size - (long)OFF_HC;
    int CT = (int)(room / 65536);          // in 128-slot tiles
    if (CT > MAXT) CT = MAXT;
    if (CT < 16) CT = 16;
    zero_out_kernel<<<dim3((NTOK * DDIM) / 1024), 256, 0, stream>>>(out);
    for (int t0 = 0; t0 < MAXT; t0 += CT) {
      int ct = (MAXT - t0 < CT) ? (MAXT - t0) : CT;
      gemm1_kernel<<<dim3(ct * 2, HDIM / 128), 256, 0, stream>>>(
          xbf, w1bf, b1, texp, perm, Hc, t0 * 2);
      gemm2_fb_kernel<<<dim3(ct * 2, DDIM / 128), 256, 0, stream>>>(
          Hc, w2bf, b2, texp, perm, wsl, out, t0 * 2);
    }
  }
}

// Round 16
// 141.640 us; speedup vs baseline: 1.1410x; 1.1410x over previous
//
#include <hip/hip_runtime.h>
#include <stdint.h>

typedef unsigned short u16;
typedef __attribute__((ext_vector_type(8))) short bf16x8;
typedef __attribute__((ext_vector_type(4))) float f32x4;
typedef __attribute__((ext_vector_type(8))) u16 u16x8;
typedef __attribute__((ext_vector_type(4))) u16 u16x4;

#define NTOK 8192
#define DDIM 1024
#define HDIM 256
#define NEXP 16
#define MAXT 272            // worst-case 128-row tiles across all experts
#define MAXMT (MAXT * 2)    // 64-row m-tiles
#define MAXSLOT (MAXT * 128)

__device__ __forceinline__ u16 f2bf(float f) {
  uint32_t u = __builtin_bit_cast(uint32_t, f);
  u += 0x7FFFu + ((u >> 16) & 1u);
  return (u16)(u >> 16);
}
__device__ __forceinline__ float bf2f(u16 h) {
  return __builtin_bit_cast(float, (uint32_t)h << 16);
}

// async global->LDS, 16B per lane; dest must be linear in lane order
__device__ __forceinline__ void gll16(const void* g, void* l) {
  __builtin_amdgcn_global_load_lds((const __attribute__((address_space(1))) void*)g,
                                   (__attribute__((address_space(3))) void*)l,
                                   16, 0, 0);
}

// ---------------- fp32 -> bf16 bulk convert (w1 + w2 fused) -----------------
__global__ __launch_bounds__(256) void cvt2_kernel(const float* __restrict__ a,
                                                   const float* __restrict__ b,
                                                   u16* __restrict__ oa,
                                                   u16* __restrict__ ob,
                                                   int nba) {
  const float* in; u16* out;
  int bx = blockIdx.x;
  if (bx < nba) { in = a; out = oa; } else { in = b; out = ob; bx -= nba; }
  size_t i = ((size_t)bx * 256 + threadIdx.x) * 8;
  const float4 p = *(const float4*)(in + i);
  const float4 q = *(const float4*)(in + i + 4);
  u16x8 o;
  o[0] = f2bf(p.x); o[1] = f2bf(p.y); o[2] = f2bf(p.z); o[3] = f2bf(p.w);
  o[4] = f2bf(q.x); o[5] = f2bf(q.y); o[6] = f2bf(q.z); o[7] = f2bf(q.w);
  *(u16x8*)(out + i) = o;
}

__global__ __launch_bounds__(256) void zero_out_kernel(float* __restrict__ p) {
  size_t i = ((size_t)blockIdx.x * 256 + threadIdx.x) * 4;
  *(float4*)(p + i) = (float4){0.f, 0.f, 0.f, 0.f};
}

// ------- router v3: LDS rw (swizzled), 16 threads/token, f64 acc ------------
__global__ __launch_bounds__(256) void router_kernel(const float* __restrict__ x,
                                                     const float* __restrict__ rw,
                                                     int* __restrict__ epack,
                                                     float* __restrict__ ew,
                                                     u16* __restrict__ xbf) {
  __shared__ __align__(16) uint8_t rwlds[65536];
  const int tid = threadIdx.x;

#pragma unroll
  for (int i = 0; i < 16; ++i) {
    int byte = (i * 256 + tid) * 16;
    int sw = byte ^ (((byte >> 8) & 7) << 4);
    *(float4*)(rwlds + sw) = *(const float4*)((const uint8_t*)rw + byte);
  }
  __syncthreads();

  const int lane = tid & 63, wid = tid >> 6;
  const int s = lane & 15;                 // strip: d in [s*64, s*64+64)
  const int tok = blockIdx.x * 16 + wid * 4 + (lane >> 4);
  const float* xrow = x + (size_t)tok * DDIM;
  u16* xbrow = xbf + (size_t)tok * DDIM;

  double acc[NEXP];
#pragma unroll
  for (int e = 0; e < NEXP; ++e) acc[e] = 0.0;

#pragma unroll 4
  for (int g = 0; g < 16; ++g) {
    const int d = s * 64 + g * 4;
    float4 xv = *(const float4*)(xrow + d);
    u16x4 o;
    o[0] = f2bf(xv.x); o[1] = f2bf(xv.y); o[2] = f2bf(xv.z); o[3] = f2bf(xv.w);
    *(u16x4*)(xbrow + d) = o;
    const double x0 = xv.x, x1 = xv.y, x2 = xv.z, x3 = xv.w;
    const int roff = (s * 256 + g * 16) ^ ((s & 7) << 4);
#pragma unroll
    for (int e = 0; e < NEXP; ++e) {
      float4 rv = *(const float4*)(rwlds + e * 4096 + roff);
      acc[e] = fma(x0, (double)rv.x, acc[e]);
      acc[e] = fma(x1, (double)rv.y, acc[e]);
      acc[e] = fma(x2, (double)rv.z, acc[e]);
      acc[e] = fma(x3, (double)rv.w, acc[e]);
    }
  }

#define FOLD(H, M)                                                   \
  _Pragma("unroll") for (int i = 0; i < H; ++i) {                    \
    double send = (lane & M) ? acc[i] : acc[i + H];                  \
    double recv = __shfl_xor(send, M);                               \
    acc[i] = ((lane & M) ? acc[i + H] : acc[i]) + recv;              \
  }
  FOLD(8, 1)
  FOLD(4, 2)
  FOLD(2, 4)
  FOLD(1, 8)
#undef FOLD
  const int e_mine = ((lane & 1) << 3) | ((lane & 2) << 1) |
                     ((lane & 4) >> 1) | ((lane & 8) >> 3);

  double val = acc[0];
  double tv[4]; int tidx[4];
#pragma unroll
  for (int k = 0; k < 4; ++k) {
    double bv = val; int be = e_mine;
#pragma unroll
    for (int m = 1; m < 16; m <<= 1) {
      double ov = __shfl_xor(bv, m);
      int oe = __shfl_xor(be, m);
      if (ov > bv || (ov == bv && oe < be)) { bv = ov; be = oe; }
    }
    tv[k] = bv; tidx[k] = be;
    if (e_mine == be) val = -1.0e300;
  }

  if ((lane & 15) == 0) {
    float m0 = (float)tv[0];
    float w[4]; float sum = 0.f;
#pragma unroll
    for (int k = 0; k < 4; ++k) { w[k] = expf((float)tv[k] - m0); sum += w[k]; }
    epack[tok] = tidx[0] | (tidx[1] << 8) | (tidx[2] << 16) | (tidx[3] << 24);
#pragma unroll
    for (int k = 0; k < 4; ++k) ew[tok * 4 + k] = w[k] / sum;
  }
}

// ------- compact: per-expert deterministic slot assignment (no atomics) -----
__global__ __launch_bounds__(1024) void compact_kernel(const int* __restrict__ epack,
                                                       const float* __restrict__ ew,
                                                       int* __restrict__ texp,
                                                       int* __restrict__ perm,
                                                       float* __restrict__ wsl,
                                                       int* __restrict__ islot) {
  __shared__ int wave_cnt[16][NEXP];
  __shared__ int counts_sm[NEXP];
  __shared__ int wtot[16], wave_off[16];
  const int e = blockIdx.x;
  const int tid = threadIdx.x, lane = tid & 63, w = tid >> 6;

  int ep[8]; unsigned m[8];
#pragma unroll
  for (int j = 0; j < 8; ++j) {
    ep[j] = epack[tid * 8 + j];
    m[j] = (1u << (ep[j] & 255)) | (1u << ((ep[j] >> 8) & 255)) |
           (1u << ((ep[j] >> 16) & 255)) | (1u << ((ep[j] >> 24) & 255));
  }
#pragma unroll
  for (int ee = 0; ee < NEXP; ++ee) {
    int c = 0;
#pragma unroll
    for (int j = 0; j < 8; ++j) c += (m[j] >> ee) & 1u;
#pragma unroll
    for (int off = 32; off > 0; off >>= 1) c += __shfl_xor(c, off);
    if (lane == 0) wave_cnt[w][ee] = c;
  }
  unsigned fm = 0;
#pragma unroll
  for (int j = 0; j < 8; ++j) fm |= ((m[j] >> e) & 1u) << j;
  int s = __popc(fm);
  int incl = s;
#pragma unroll
  for (int d = 1; d < 64; d <<= 1) {
    int t2 = __shfl_up(incl, d);
    if (lane >= d) incl += t2;
  }
  if (lane == 63) wtot[w] = incl;
  __syncthreads();
  if (tid < NEXP) {
    int c = 0;
    for (int w2 = 0; w2 < 16; ++w2) c += wave_cnt[w2][tid];
    counts_sm[tid] = c;
  }
  if (tid == 0) {
    int run = 0;
    for (int w2 = 0; w2 < 16; ++w2) { wave_off[w2] = run; run += wtot[w2]; }
  }
  __syncthreads();
  int base = 0;
  for (int ee = 0; ee < NEXP; ++ee)
    if (ee < e) base += ((counts_sm[ee] + 127) >> 7) << 7;
  int pos = base + wave_off[w] + (incl - s);
#pragma unroll
  for (int j = 0; j < 8; ++j) {
    if ((fm >> j) & 1u) {
      int tok = tid * 8 + j;
      int b0 = ep[j] & 255, b1 = (ep[j] >> 8) & 255, b2_ = (ep[j] >> 16) & 255;
      int k = (b0 == e) ? 0 : ((b1 == e) ? 1 : ((b2_ == e) ? 2 : 3));
      perm[pos] = tok;
      wsl[pos] = ew[tok * 4 + k];
      islot[tok * 4 + k] = pos;
      ++pos;
    }
  }
  int cnt = counts_sm[e];
  int pad = (((cnt + 127) >> 7) << 7) - cnt;
  if (tid < pad) { perm[base + cnt + tid] = 0; wsl[base + cnt + tid] = 0.f; }
  if (e == 0 && tid == 0) {
    int tc = 0;
    for (int ee = 0; ee < NEXP; ++ee) {
      int nt = (counts_sm[ee] + 127) >> 7;
      for (int i = 0; i < nt; ++i) texp[tc++] = ee;
    }
    for (; tc < MAXT; ++tc) texp[tc] = -1;
  }
}

// ---------------- staging (pre-swizzled source -> linear LDS) ---------------
// 128 rows x 64 cols (16 KB): 4 units/thread
__device__ __forceinline__ void stage128(const u16* __restrict__ base, int ld,
                                         int kbase, uint8_t* dst, int tid) {
#pragma unroll
  for (int i = 0; i < 4; ++i) {
    int u = i * 256 + tid;
    int row = u >> 3, g = u & 7;
    gll16(base + (size_t)row * ld + kbase + ((g ^ (row & 7)) << 3), dst + u * 16);
  }
}
// 64 rows x 64 cols (8 KB): 2 units/thread
__device__ __forceinline__ void stage64(const u16* __restrict__ base, int ld,
                                        int kbase, uint8_t* dst, int tid) {
#pragma unroll
  for (int i = 0; i < 2; ++i) {
    int u = i * 256 + tid;
    int row = u >> 3, g = u & 7;
    gll16(base + (size_t)row * ld + kbase + ((g ^ (row & 7)) << 3), dst + u * 16);
  }
}
// gather 64 rows of x by token (8 KB): 2 units/thread
__device__ __forceinline__ void stage_gather64(const u16* __restrict__ xbf,
                                               const int tok[2], int kbase,
                                               uint8_t* dst, int tid) {
#pragma unroll
  for (int i = 0; i < 2; ++i) {
    int u = i * 256 + tid;
    int g = u & 7;
    gll16(xbf + (size_t)tok[i] * DDIM + kbase + ((g ^ ((u >> 3) & 7)) << 3), dst + u * 16);
  }
}

// 64x128 tile, 4 waves (2m x 2n), wave 32x64
__device__ __forceinline__ void mma64(const uint8_t* Ab, const uint8_t* Bb,
                                      f32x4 acc[2][4], int wm, int wn,
                                      int lrow, int lk) {
#pragma unroll
  for (int s = 0; s < 2; ++s) {
    bf16x8 af[2], bfr[4];
#pragma unroll
    for (int f = 0; f < 2; ++f) {
      int ar = wm * 32 + f * 16 + lrow;
      af[f] = *(const bf16x8*)(Ab + ar * 128 + ((((s << 2) | lk) ^ (ar & 7)) << 4));
    }
#pragma unroll
    for (int f = 0; f < 4; ++f) {
      int br = wn * 64 + f * 16 + lrow;
      bfr[f] = *(const bf16x8*)(Bb + br * 128 + ((((s << 2) | lk) ^ (br & 7)) << 4));
    }
#pragma unroll
    for (int i = 0; i < 2; ++i)
#pragma unroll
      for (int j = 0; j < 4; ++j)
        acc[i][j] = __builtin_amdgcn_mfma_f32_16x16x32_bf16(af[i], bfr[j], acc[i][j], 0, 0, 0);
  }
}

// ------- GEMM1: Hc[slot-64-tile] = relu(x[perm] @ W1e^T + b1e) --------------
// grid (n_mtiles, HDIM/128). 64-row m-tiles, dbuf prefetch. (R9 proven)
__global__ __launch_bounds__(256) void gemm1_kernel(const u16* __restrict__ xbf,
                                                    const u16* __restrict__ w1bf,
                                                    const float* __restrict__ b1,
                                                    const int* __restrict__ texp,
                                                    const int* __restrict__ perm,
                                                    u16* __restrict__ Hc, int mt0) {
  __shared__ __align__(16) uint8_t smem[2][24576];  // A 8KB @0, B 16KB @8192
  const int mt = mt0 + blockIdx.x;
  const int e = (mt < MAXMT) ? texp[mt >> 1] : -1;
  if (e < 0) return;
  const int n0 = blockIdx.y * 128;
  const int tid = threadIdx.x;
  const int lane = tid & 63, wid = tid >> 6;
  const int wm = wid >> 1, wn = wid & 1;
  const int lrow = lane & 15, lk = lane >> 4;

  int tok[2];
#pragma unroll
  for (int i = 0; i < 2; ++i) tok[i] = perm[mt * 64 + ((i * 256 + tid) >> 3)];
  const u16* Bsrc = w1bf + ((size_t)e * HDIM + n0) * DDIM;

  f32x4 acc[2][4];
#pragma unroll
  for (int i = 0; i < 2; ++i)
#pragma unroll
    for (int j = 0; j < 4; ++j) acc[i][j] = (f32x4){0.f, 0.f, 0.f, 0.f};

  stage_gather64(xbf, tok, 0, smem[0], tid);
  stage128(Bsrc, DDIM, 0, smem[0] + 8192, tid);
  __syncthreads();
  int cur = 0;
  for (int kt = 0; kt < 16; ++kt) {
    if (kt < 15) {
      stage_gather64(xbf, tok, (kt + 1) * 64, smem[cur ^ 1], tid);
      stage128(Bsrc, DDIM, (kt + 1) * 64, smem[cur ^ 1] + 8192, tid);
    }
    mma64(smem[cur], smem[cur] + 8192, acc, wm, wn, lrow, lk);
    __syncthreads();
    cur ^= 1;
  }
#pragma unroll
  for (int j = 0; j < 4; ++j) {
    int n = n0 + wn * 64 + j * 16 + lrow;
    float bias = b1[e * HDIM + n];
#pragma unroll
    for (int i = 0; i < 2; ++i) {
      int rloc = (mt - mt0) * 64 + wm * 32 + i * 16 + lk * 4;
#pragma unroll
      for (int r = 0; r < 4; ++r) {
        float h = fmaxf(acc[i][j][r] + bias, 0.f);
        Hc[((size_t)rloc + r) * HDIM + n] = f2bf(h);
      }
    }
  }
}

// ------- GEMM2 main: y -> ybuf. grid (n_mtiles, ybN/128), dbuf (R9) ---------
__global__ __launch_bounds__(256) void gemm2_main_kernel(const u16* __restrict__ Hc,
                                                         const u16* __restrict__ w2bf,
                                                         const float* __restrict__ b2,
                                                         const int* __restrict__ texp,
                                                         u16* __restrict__ ybuf,
                                                         int nbase, int NC) {
  __shared__ __align__(16) uint8_t smem[2][24576];
  const int mt = blockIdx.x;
  const int e = texp[mt >> 1];
  if (e < 0) return;
  const int nl0 = blockIdx.y * 128;
  const int tid = threadIdx.x;
  const int lane = tid & 63, wid = tid >> 6;
  const int wm = wid >> 1, wn = wid & 1;
  const int lrow = lane & 15, lk = lane >> 4;

  const u16* Asrc = Hc + (size_t)mt * 64 * HDIM;
  const u16* Bsrc = w2bf + ((size_t)e * DDIM + nbase + nl0) * HDIM;

  f32x4 acc[2][4];
#pragma unroll
  for (int i = 0; i < 2; ++i)
#pragma unroll
    for (int j = 0; j < 4; ++j) acc[i][j] = (f32x4){0.f, 0.f, 0.f, 0.f};

  stage64(Asrc, HDIM, 0, smem[0], tid);
  stage128(Bsrc, HDIM, 0, smem[0] + 8192, tid);
  __syncthreads();
  int cur = 0;
  for (int kt = 0; kt < 4; ++kt) {
    if (kt < 3) {
      stage64(Asrc, HDIM, (kt + 1) * 64, smem[cur ^ 1], tid);
      stage128(Bsrc, HDIM, (kt + 1) * 64, smem[cur ^ 1] + 8192, tid);
    }
    mma64(smem[cur], smem[cur] + 8192, acc, wm, wn, lrow, lk);
    __syncthreads();
    cur ^= 1;
  }
  float bias[4];
#pragma unroll
  for (int j = 0; j < 4; ++j)
    bias[j] = b2[e * DDIM + nbase + nl0 + wn * 64 + j * 16 + lrow];
#pragma unroll
  for (int i = 0; i < 2; ++i) {
#pragma unroll
    for (int r = 0; r < 4; ++r) {
      int slot = mt * 64 + wm * 32 + i * 16 + lk * 4 + r;
#pragma unroll
      for (int j = 0; j < 4; ++j) {
        int nloc = nl0 + wn * 64 + j * 16 + lrow;
        float h = fmaxf(acc[i][j][r] + bias[j], 0.f);
        ybuf[(size_t)slot * NC + nloc] = f2bf(h);
      }
    }
  }
}

// ------- GEMM2 fallback (atomic accumulate) ---------------------------------
__global__ __launch_bounds__(256) void gemm2_fb_kernel(const u16* __restrict__ Hc,
                                                       const u16* __restrict__ w2bf,
                                                       const float* __restrict__ b2,
                                                       const int* __restrict__ texp,
                                                       const int* __restrict__ perm,
                                                       const float* __restrict__ wsl,
                                                       float* __restrict__ out, int mt0) {
  __shared__ __align__(16) uint8_t smem[2][24576];
  const int mt = mt0 + blockIdx.x;
  const int e = (mt < MAXMT) ? texp[mt >> 1] : -1;
  if (e < 0) return;
  const int nl0 = blockIdx.y * 128;
  const int tid = threadIdx.x;
  const int lane = tid & 63, wid = tid >> 6;
  const int wm = wid >> 1, wn = wid & 1;
  const int lrow = lane & 15, lk = lane >> 4;

  const u16* Asrc = Hc + (size_t)(mt - mt0) * 64 * HDIM;
  const u16* Bsrc = w2bf + ((size_t)e * DDIM + nl0) * HDIM;

  f32x4 acc[2][4];
#pragma unroll
  for (int i = 0; i < 2; ++i)
#pragma unroll
    for (int j = 0; j < 4; ++j) acc[i][j] = (f32x4){0.f, 0.f, 0.f, 0.f};

  stage64(Asrc, HDIM, 0, smem[0], tid);
  stage128(Bsrc, HDIM, 0, smem[0] + 8192, tid);
  __syncthreads();
  int cur = 0;
  for (int kt = 0; kt < 4; ++kt) {
    if (kt < 3) {
      stage64(Asrc, HDIM, (kt + 1) * 64, smem[cur ^ 1], tid);
      stage128(Bsrc, HDIM, (kt + 1) * 64, smem[cur ^ 1] + 8192, tid);
    }
    mma64(smem[cur], smem[cur] + 8192, acc, wm, wn, lrow, lk);
    __syncthreads();
    cur ^= 1;
  }
  float bias[4];
#pragma unroll
  for (int j = 0; j < 4; ++j)
    bias[j] = b2[e * DDIM + nl0 + wn * 64 + j * 16 + lrow];
#pragma unroll
  for (int i = 0; i < 2; ++i) {
#pragma unroll
    for (int r = 0; r < 4; ++r) {
      int slot = mt * 64 + wm * 32 + i * 16 + lk * 4 + r;
      int tokn = perm[slot];
      float w = wsl[slot];
#pragma unroll
      for (int j = 0; j < 4; ++j) {
        int n = nl0 + wn * 64 + j * 16 + lrow;
        float h = fmaxf(acc[i][j][r] + bias[j], 0.f);
        atomicAdd(&out[(size_t)tokn * DDIM + n], w * h);
      }
    }
  }
}

// ------- combine: 16 cols/thread --------------------------------------------
__global__ __launch_bounds__(256) void combine_kernel(const u16* __restrict__ ybuf,
                                                      const float* __restrict__ ew,
                                                      const int* __restrict__ islot,
                                                      float* __restrict__ out,
                                                      int n0, int NC, int cshift) {
  int gid = blockIdx.x * 256 + threadIdx.x;
  int t = gid >> cshift;
  int c = (gid & ((1 << cshift) - 1)) << 4;
  const int4 sl = *(const int4*)(islot + t * 4);
  const float4 w = *(const float4*)(ew + t * 4);
  float a[16];
#pragma unroll
  for (int k = 0; k < 16; ++k) a[k] = 0.f;
#define ACCROW(SL, W)                                                      \
  {                                                                        \
    u16x8 y0 = *(const u16x8*)(ybuf + (size_t)(SL)*NC + c);                \
    u16x8 y1 = *(const u16x8*)(ybuf + (size_t)(SL)*NC + c + 8);            \
    _Pragma("unroll") for (int k = 0; k < 8; ++k) {                        \
      a[k] += (W)*bf2f(y0[k]); a[8 + k] += (W)*bf2f(y1[k]);                \
    }                                                                      \
  }
  ACCROW(sl.x, w.x); ACCROW(sl.y, w.y); ACCROW(sl.z, w.z); ACCROW(sl.w, w.w);
#undef ACCROW
  float* o = out + (size_t)t * DDIM + n0 + c;
#pragma unroll
  for (int k = 0; k < 16; k += 4)
    *(float4*)(o + k) = (float4){a[k], a[k + 1], a[k + 2], a[k + 3]};
}

// ---------------------------------------------------------------------------
extern "C" void kernel_launch(void* const* d_in, const int* in_sizes, int n_in,
                              void* d_out, int out_size, void* d_ws, size_t ws_size,
                              hipStream_t stream) {
  const float* x = (const float*)d_in[0];
  const float* route_w = (const float*)d_in[1];
  const float* w1 = (const float*)d_in[2];
  const float* b1 = (const float*)d_in[3];
  const float* w2 = (const float*)d_in[4];
  const float* b2 = (const float*)d_in[5];
  float* out = (float*)d_out;

  uint8_t* ws = (uint8_t*)d_ws;
  const size_t OFF_EPACK = 0;                      // 8192 ints  = 32 KB
  const size_t OFF_EW    = 32768;                  // 32768 f    = 128 KB
  const size_t OFF_ISLOT = 163840;                 // 32768 ints = 128 KB
  const size_t OFF_TEXP  = 294912;                 // 272 ints
  const size_t OFF_PERM  = 296960;                 // 34816 ints
  const size_t OFF_WSL   = 436224;                 // 34816 f
  const size_t OFF_X     = 1048576;                // 16.78 MB bf16 x
  const size_t OFF_W1    = OFF_X + (size_t)NTOK * DDIM * 2;
  const size_t OFF_W2    = OFF_W1 + (size_t)NEXP * HDIM * DDIM * 2;
  const size_t OFF_HC    = OFF_W2 + (size_t)NEXP * DDIM * HDIM * 2;
  const size_t OFF_Y     = OFF_HC + (size_t)MAXSLOT * HDIM * 2;

  int* epack  = (int*)(ws + OFF_EPACK);
  float* ew   = (float*)(ws + OFF_EW);
  int* islot  = (int*)(ws + OFF_ISLOT);
  int* texp   = (int*)(ws + OFF_TEXP);
  int* perm   = (int*)(ws + OFF_PERM);
  float* wsl  = (float*)(ws + OFF_WSL);
  u16* xbf    = (u16*)(ws + OFF_X);
  u16* w1bf   = (u16*)(ws + OFF_W1);
  u16* w2bf   = (u16*)(ws + OFF_W2);
  u16* Hc     = (u16*)(ws + OFF_HC);
  u16* ybuf   = (u16*)(ws + OFF_Y);

  const int nba = (NEXP * HDIM * DDIM) / 2048;
  cvt2_kernel<<<dim3(nba * 2), 256, 0, stream>>>(w1, w2, w1bf, w2bf, nba);
  router_kernel<<<dim3(NTOK / 16), 256, 0, stream>>>(x, route_w, epack, ew, xbf);
  compact_kernel<<<dim3(NEXP), 1024, 0, stream>>>(epack, ew, texp, perm, wsl, islot);

  // ybuf chunk width based on available workspace (prefer 1024: single pass)
  int ybN = 0;
  for (int cand = 1024; cand >= 128; cand >>= 1) {
    if (ws_size >= OFF_Y + (size_t)MAXSLOT * cand * 2) { ybN = cand; break; }
  }

  if (ybN > 0) {
    gemm1_kernel<<<dim3(MAXMT, HDIM / 128), 256, 0, stream>>>(xbf, w1bf, b1, texp, perm, Hc, 0);
    int cshift = __builtin_ctz(ybN >> 4);
    for (int nb = 0; nb < DDIM; nb += ybN) {
      gemm2_main_kernel<<<dim3(MAXMT, ybN / 128), 256, 0, stream>>>(
          Hc, w2bf, b2, texp, ybuf, nb, ybN);
      combine_kernel<<<dim3((NTOK << cshift) / 256), 256, 0, stream>>>(
          ybuf, ew, islot, out, nb, ybN, cshift);
    }
  } else {
    long room = (long)ws_size - (long)OFF_HC;
    int CT = (int)(room / 65536);          // in 128-slot tiles
    if (CT > MAXT) CT = MAXT;
    if (CT < 16) CT = 16;
    zero_out_kernel<<<dim3((NTOK * DDIM) / 1024), 256, 0, stream>>>(out);
    for (int t0 = 0; t0 < MAXT; t0 += CT) {
      int ct = (MAXT - t0 < CT) ? (MAXT - t0) : CT;
      gemm1_kernel<<<dim3(ct * 2, HDIM / 128), 256, 0, stream>>>(
          xbf, w1bf, b1, texp, perm, Hc, t0 * 2);
      gemm2_fb_kernel<<<dim3(ct * 2, DDIM / 128), 256, 0, stream>>>(
          Hc, w2bf, b2, texp, perm, wsl, out, t0 * 2);
    }
  }
}

// Round 17
// 138.306 us; speedup vs baseline: 1.1685x; 1.0241x over previous
//
#include <hip/hip_runtime.h>
#include <stdint.h>

typedef unsigned short u16;
typedef __attribute__((ext_vector_type(8))) short bf16x8;
typedef __attribute__((ext_vector_type(4))) float f32x4;
typedef __attribute__((ext_vector_type(8))) u16 u16x8;
typedef __attribute__((ext_vector_type(4))) u16 u16x4;

#define NTOK 8192
#define DDIM 1024
#define HDIM 256
#define NEXP 16
#define MAXT 272            // worst-case 128-row tiles across all experts
#define MAXMT (MAXT * 2)    // 64-row m-tiles
#define MAXSLOT (MAXT * 128)

__device__ __forceinline__ u16 f2bf(float f) {
  uint32_t u = __builtin_bit_cast(uint32_t, f);
  u += 0x7FFFu + ((u >> 16) & 1u);
  return (u16)(u >> 16);
}
__device__ __forceinline__ float bf2f(u16 h) {
  return __builtin_bit_cast(float, (uint32_t)h << 16);
}

// async global->LDS, 16B per lane; dest must be linear in lane order
__device__ __forceinline__ void gll16(const void* g, void* l) {
  __builtin_amdgcn_global_load_lds((const __attribute__((address_space(1))) void*)g,
                                   (__attribute__((address_space(3))) void*)l,
                                   16, 0, 0);
}

// ---------------- fp32 -> bf16 bulk convert (w1 + w2 fused) -----------------
__global__ __launch_bounds__(256) void cvt2_kernel(const float* __restrict__ a,
                                                   const float* __restrict__ b,
                                                   u16* __restrict__ oa,
                                                   u16* __restrict__ ob,
                                                   int nba) {
  const float* in; u16* out;
  int bx = blockIdx.x;
  if (bx < nba) { in = a; out = oa; } else { in = b; out = ob; bx -= nba; }
  size_t i = ((size_t)bx * 256 + threadIdx.x) * 8;
  const float4 p = *(const float4*)(in + i);
  const float4 q = *(const float4*)(in + i + 4);
  u16x8 o;
  o[0] = f2bf(p.x); o[1] = f2bf(p.y); o[2] = f2bf(p.z); o[3] = f2bf(p.w);
  o[4] = f2bf(q.x); o[5] = f2bf(q.y); o[6] = f2bf(q.z); o[7] = f2bf(q.w);
  *(u16x8*)(out + i) = o;
}

__global__ __launch_bounds__(256) void zero_out_kernel(float* __restrict__ p) {
  size_t i = ((size_t)blockIdx.x * 256 + threadIdx.x) * 4;
  *(float4*)(p + i) = (float4){0.f, 0.f, 0.f, 0.f};
}

// ------- router v3: LDS rw (swizzled), 16 threads/token, f64 acc ------------
__global__ __launch_bounds__(256) void router_kernel(const float* __restrict__ x,
                                                     const float* __restrict__ rw,
                                                     int* __restrict__ epack,
                                                     float* __restrict__ ew,
                                                     u16* __restrict__ xbf) {
  __shared__ __align__(16) uint8_t rwlds[65536];
  const int tid = threadIdx.x;

#pragma unroll
  for (int i = 0; i < 16; ++i) {
    int byte = (i * 256 + tid) * 16;
    int sw = byte ^ (((byte >> 8) & 7) << 4);
    *(float4*)(rwlds + sw) = *(const float4*)((const uint8_t*)rw + byte);
  }
  __syncthreads();

  const int lane = tid & 63, wid = tid >> 6;
  const int s = lane & 15;                 // strip: d in [s*64, s*64+64)
  const int tok = blockIdx.x * 16 + wid * 4 + (lane >> 4);
  const float* xrow = x + (size_t)tok * DDIM;
  u16* xbrow = xbf + (size_t)tok * DDIM;

  double acc[NEXP];
#pragma unroll
  for (int e = 0; e < NEXP; ++e) acc[e] = 0.0;

#pragma unroll 4
  for (int g = 0; g < 16; ++g) {
    const int d = s * 64 + g * 4;
    float4 xv = *(const float4*)(xrow + d);
    u16x4 o;
    o[0] = f2bf(xv.x); o[1] = f2bf(xv.y); o[2] = f2bf(xv.z); o[3] = f2bf(xv.w);
    *(u16x4*)(xbrow + d) = o;
    const double x0 = xv.x, x1 = xv.y, x2 = xv.z, x3 = xv.w;
    const int roff = (s * 256 + g * 16) ^ ((s & 7) << 4);
#pragma unroll
    for (int e = 0; e < NEXP; ++e) {
      float4 rv = *(const float4*)(rwlds + e * 4096 + roff);
      acc[e] = fma(x0, (double)rv.x, acc[e]);
      acc[e] = fma(x1, (double)rv.y, acc[e]);
      acc[e] = fma(x2, (double)rv.z, acc[e]);
      acc[e] = fma(x3, (double)rv.w, acc[e]);
    }
  }

#define FOLD(H, M)                                                   \
  _Pragma("unroll") for (int i = 0; i < H; ++i) {                    \
    double send = (lane & M) ? acc[i] : acc[i + H];                  \
    double recv = __shfl_xor(send, M);                               \
    acc[i] = ((lane & M) ? acc[i + H] : acc[i]) + recv;              \
  }
  FOLD(8, 1)
  FOLD(4, 2)
  FOLD(2, 4)
  FOLD(1, 8)
#undef FOLD
  const int e_mine = ((lane & 1) << 3) | ((lane & 2) << 1) |
                     ((lane & 4) >> 1) | ((lane & 8) >> 3);

  double val = acc[0];
  double tv[4]; int tidx[4];
#pragma unroll
  for (int k = 0; k < 4; ++k) {
    double bv = val; int be = e_mine;
#pragma unroll
    for (int m = 1; m < 16; m <<= 1) {
      double ov = __shfl_xor(bv, m);
      int oe = __shfl_xor(be, m);
      if (ov > bv || (ov == bv && oe < be)) { bv = ov; be = oe; }
    }
    tv[k] = bv; tidx[k] = be;
    if (e_mine == be) val = -1.0e300;
  }

  if ((lane & 15) == 0) {
    float m0 = (float)tv[0];
    float w[4]; float sum = 0.f;
#pragma unroll
    for (int k = 0; k < 4; ++k) { w[k] = expf((float)tv[k] - m0); sum += w[k]; }
    epack[tok] = tidx[0] | (tidx[1] << 8) | (tidx[2] << 16) | (tidx[3] << 24);
#pragma unroll
    for (int k = 0; k < 4; ++k) ew[tok * 4 + k] = w[k] / sum;
  }
}

// ------- compact: per-expert deterministic slot assignment (no atomics) -----
__global__ __launch_bounds__(1024) void compact_kernel(const int* __restrict__ epack,
                                                       const float* __restrict__ ew,
                                                       int* __restrict__ texp,
                                                       int* __restrict__ perm,
                                                       float* __restrict__ wsl,
                                                       int* __restrict__ islot) {
  __shared__ int wave_cnt[16][NEXP];
  __shared__ int counts_sm[NEXP];
  __shared__ int wtot[16], wave_off[16];
  const int e = blockIdx.x;
  const int tid = threadIdx.x, lane = tid & 63, w = tid >> 6;

  int ep[8]; unsigned m[8];
#pragma unroll
  for (int j = 0; j < 8; ++j) {
    ep[j] = epack[tid * 8 + j];
    m[j] = (1u << (ep[j] & 255)) | (1u << ((ep[j] >> 8) & 255)) |
           (1u << ((ep[j] >> 16) & 255)) | (1u << ((ep[j] >> 24) & 255));
  }
#pragma unroll
  for (int ee = 0; ee < NEXP; ++ee) {
    int c = 0;
#pragma unroll
    for (int j = 0; j < 8; ++j) c += (m[j] >> ee) & 1u;
#pragma unroll
    for (int off = 32; off > 0; off >>= 1) c += __shfl_xor(c, off);
    if (lane == 0) wave_cnt[w][ee] = c;
  }
  unsigned fm = 0;
#pragma unroll
  for (int j = 0; j < 8; ++j) fm |= ((m[j] >> e) & 1u) << j;
  int s = __popc(fm);
  int incl = s;
#pragma unroll
  for (int d = 1; d < 64; d <<= 1) {
    int t2 = __shfl_up(incl, d);
    if (lane >= d) incl += t2;
  }
  if (lane == 63) wtot[w] = incl;
  __syncthreads();
  if (tid < NEXP) {
    int c = 0;
    for (int w2 = 0; w2 < 16; ++w2) c += wave_cnt[w2][tid];
    counts_sm[tid] = c;
  }
  if (tid == 0) {
    int run = 0;
    for (int w2 = 0; w2 < 16; ++w2) { wave_off[w2] = run; run += wtot[w2]; }
  }
  __syncthreads();
  int base = 0;
  for (int ee = 0; ee < NEXP; ++ee)
    if (ee < e) base += ((counts_sm[ee] + 127) >> 7) << 7;
  int pos = base + wave_off[w] + (incl - s);
#pragma unroll
  for (int j = 0; j < 8; ++j) {
    if ((fm >> j) & 1u) {
      int tok = tid * 8 + j;
      int b0 = ep[j] & 255, b1 = (ep[j] >> 8) & 255, b2_ = (ep[j] >> 16) & 255;
      int k = (b0 == e) ? 0 : ((b1 == e) ? 1 : ((b2_ == e) ? 2 : 3));
      perm[pos] = tok;
      wsl[pos] = ew[tok * 4 + k];
      islot[tok * 4 + k] = pos;
      ++pos;
    }
  }
  int cnt = counts_sm[e];
  int pad = (((cnt + 127) >> 7) << 7) - cnt;
  if (tid < pad) { perm[base + cnt + tid] = 0; wsl[base + cnt + tid] = 0.f; }
  if (e == 0 && tid == 0) {
    int tc = 0;
    for (int ee = 0; ee < NEXP; ++ee) {
      int nt = (counts_sm[ee] + 127) >> 7;
      for (int i = 0; i < nt; ++i) texp[tc++] = ee;
    }
    for (; tc < MAXT; ++tc) texp[tc] = -1;
  }
}

// ---------------- staging (pre-swizzled source -> linear LDS) ---------------
// 128 rows x 64 cols (16 KB): 4 units/thread
__device__ __forceinline__ void stage128(const u16* __restrict__ base, int ld,
                                         int kbase, uint8_t* dst, int tid) {
#pragma unroll
  for (int i = 0; i < 4; ++i) {
    int u = i * 256 + tid;
    int row = u >> 3, g = u & 7;
    gll16(base + (size_t)row * ld + kbase + ((g ^ (row & 7)) << 3), dst + u * 16);
  }
}
// 64 rows x 64 cols (8 KB): 2 units/thread
__device__ __forceinline__ void stage64(const u16* __restrict__ base, int ld,
                                        int kbase, uint8_t* dst, int tid) {
#pragma unroll
  for (int i = 0; i < 2; ++i) {
    int u = i * 256 + tid;
    int row = u >> 3, g = u & 7;
    gll16(base + (size_t)row * ld + kbase + ((g ^ (row & 7)) << 3), dst + u * 16);
  }
}
// gather 64 rows of x by token (8 KB): 2 units/thread
__device__ __forceinline__ void stage_gather64(const u16* __restrict__ xbf,
                                               const int tok[2], int kbase,
                                               uint8_t* dst, int tid) {
#pragma unroll
  for (int i = 0; i < 2; ++i) {
    int u = i * 256 + tid;
    int g = u & 7;
    gll16(xbf + (size_t)tok[i] * DDIM + kbase + ((g ^ ((u >> 3) & 7)) << 3), dst + u * 16);
  }
}

// 64x128 tile, 4 waves (2m x 2n), wave 32x64
__device__ __forceinline__ void mma64(const uint8_t* Ab, const uint8_t* Bb,
                                      f32x4 acc[2][4], int wm, int wn,
                                      int lrow, int lk) {
#pragma unroll
  for (int s = 0; s < 2; ++s) {
    bf16x8 af[2], bfr[4];
#pragma unroll
    for (int f = 0; f < 2; ++f) {
      int ar = wm * 32 + f * 16 + lrow;
      af[f] = *(const bf16x8*)(Ab + ar * 128 + ((((s << 2) | lk) ^ (ar & 7)) << 4));
    }
#pragma unroll
    for (int f = 0; f < 4; ++f) {
      int br = wn * 64 + f * 16 + lrow;
      bfr[f] = *(const bf16x8*)(Bb + br * 128 + ((((s << 2) | lk) ^ (br & 7)) << 4));
    }
#pragma unroll
    for (int i = 0; i < 2; ++i)
#pragma unroll
      for (int j = 0; j < 4; ++j)
        acc[i][j] = __builtin_amdgcn_mfma_f32_16x16x32_bf16(af[i], bfr[j], acc[i][j], 0, 0, 0);
  }
}

// ------- GEMM1: Hc[slot-64-tile] = relu(x[perm] @ W1e^T + b1e) --------------
// grid (n_mtiles, HDIM/128). 64-row m-tiles, dbuf prefetch. (R9 proven)
__global__ __launch_bounds__(256) void gemm1_kernel(const u16* __restrict__ xbf,
                                                    const u16* __restrict__ w1bf,
                                                    const float* __restrict__ b1,
                                                    const int* __restrict__ texp,
                                                    const int* __restrict__ perm,
                                                    u16* __restrict__ Hc, int mt0) {
  __shared__ __align__(16) uint8_t smem[2][24576];  // A 8KB @0, B 16KB @8192
  const int mt = mt0 + blockIdx.x;
  const int e = (mt < MAXMT) ? texp[mt >> 1] : -1;
  if (e < 0) return;
  const int n0 = blockIdx.y * 128;
  const int tid = threadIdx.x;
  const int lane = tid & 63, wid = tid >> 6;
  const int wm = wid >> 1, wn = wid & 1;
  const int lrow = lane & 15, lk = lane >> 4;

  int tok[2];
#pragma unroll
  for (int i = 0; i < 2; ++i) tok[i] = perm[mt * 64 + ((i * 256 + tid) >> 3)];
  const u16* Bsrc = w1bf + ((size_t)e * HDIM + n0) * DDIM;

  f32x4 acc[2][4];
#pragma unroll
  for (int i = 0; i < 2; ++i)
#pragma unroll
    for (int j = 0; j < 4; ++j) acc[i][j] = (f32x4){0.f, 0.f, 0.f, 0.f};

  stage_gather64(xbf, tok, 0, smem[0], tid);
  stage128(Bsrc, DDIM, 0, smem[0] + 8192, tid);
  __syncthreads();
  int cur = 0;
  for (int kt = 0; kt < 16; ++kt) {
    if (kt < 15) {
      stage_gather64(xbf, tok, (kt + 1) * 64, smem[cur ^ 1], tid);
      stage128(Bsrc, DDIM, (kt + 1) * 64, smem[cur ^ 1] + 8192, tid);
    }
    mma64(smem[cur], smem[cur] + 8192, acc, wm, wn, lrow, lk);
    __syncthreads();
    cur ^= 1;
  }
#pragma unroll
  for (int j = 0; j < 4; ++j) {
    int n = n0 + wn * 64 + j * 16 + lrow;
    float bias = b1[e * HDIM + n];
#pragma unroll
    for (int i = 0; i < 2; ++i) {
      int rloc = (mt - mt0) * 64 + wm * 32 + i * 16 + lk * 4;
#pragma unroll
      for (int r = 0; r < 4; ++r) {
        float h = fmaxf(acc[i][j][r] + bias, 0.f);
        Hc[((size_t)rloc + r) * HDIM + n] = f2bf(h);
      }
    }
  }
}

// ------- GEMM2 main: y -> ybuf. SINGLE-BUFFER 24KB -> 6 blocks/CU -----------
__global__ __launch_bounds__(256) void gemm2_main_kernel(const u16* __restrict__ Hc,
                                                         const u16* __restrict__ w2bf,
                                                         const float* __restrict__ b2,
                                                         const int* __restrict__ texp,
                                                         u16* __restrict__ ybuf,
                                                         int nbase, int NC) {
  __shared__ __align__(16) uint8_t smem[24576];  // A 8KB @0, B 16KB @8192
  const int mt = blockIdx.x;
  const int e = texp[mt >> 1];
  if (e < 0) return;
  const int nl0 = blockIdx.y * 128;
  const int tid = threadIdx.x;
  const int lane = tid & 63, wid = tid >> 6;
  const int wm = wid >> 1, wn = wid & 1;
  const int lrow = lane & 15, lk = lane >> 4;

  const u16* Asrc = Hc + (size_t)mt * 64 * HDIM;
  const u16* Bsrc = w2bf + ((size_t)e * DDIM + nbase + nl0) * HDIM;

  f32x4 acc[2][4];
#pragma unroll
  for (int i = 0; i < 2; ++i)
#pragma unroll
    for (int j = 0; j < 4; ++j) acc[i][j] = (f32x4){0.f, 0.f, 0.f, 0.f};

  for (int kt = 0; kt < 4; ++kt) {
    stage64(Asrc, HDIM, kt * 64, smem, tid);
    stage128(Bsrc, HDIM, kt * 64, smem + 8192, tid);
    __syncthreads();
    mma64(smem, smem + 8192, acc, wm, wn, lrow, lk);
    __syncthreads();
  }
  float bias[4];
#pragma unroll
  for (int j = 0; j < 4; ++j)
    bias[j] = b2[e * DDIM + nbase + nl0 + wn * 64 + j * 16 + lrow];
#pragma unroll
  for (int i = 0; i < 2; ++i) {
#pragma unroll
    for (int r = 0; r < 4; ++r) {
      int slot = mt * 64 + wm * 32 + i * 16 + lk * 4 + r;
#pragma unroll
      for (int j = 0; j < 4; ++j) {
        int nloc = nl0 + wn * 64 + j * 16 + lrow;
        float h = fmaxf(acc[i][j][r] + bias[j], 0.f);
        ybuf[(size_t)slot * NC + nloc] = f2bf(h);
      }
    }
  }
}

// ------- GEMM2 fallback (atomic accumulate), single-buffer ------------------
__global__ __launch_bounds__(256) void gemm2_fb_kernel(const u16* __restrict__ Hc,
                                                       const u16* __restrict__ w2bf,
                                                       const float* __restrict__ b2,
                                                       const int* __restrict__ texp,
                                                       const int* __restrict__ perm,
                                                       const float* __restrict__ wsl,
                                                       float* __restrict__ out, int mt0) {
  __shared__ __align__(16) uint8_t smem[24576];
  const int mt = mt0 + blockIdx.x;
  const int e = (mt < MAXMT) ? texp[mt >> 1] : -1;
  if (e < 0) return;
  const int nl0 = blockIdx.y * 128;
  const int tid = threadIdx.x;
  const int lane = tid & 63, wid = tid >> 6;
  const int wm = wid >> 1, wn = wid & 1;
  const int lrow = lane & 15, lk = lane >> 4;

  const u16* Asrc = Hc + (size_t)(mt - mt0) * 64 * HDIM;
  const u16* Bsrc = w2bf + ((size_t)e * DDIM + nl0) * HDIM;

  f32x4 acc[2][4];
#pragma unroll
  for (int i = 0; i < 2; ++i)
#pragma unroll
    for (int j = 0; j < 4; ++j) acc[i][j] = (f32x4){0.f, 0.f, 0.f, 0.f};

  for (int kt = 0; kt < 4; ++kt) {
    stage64(Asrc, HDIM, kt * 64, smem, tid);
    stage128(Bsrc, HDIM, kt * 64, smem + 8192, tid);
    __syncthreads();
    mma64(smem, smem + 8192, acc, wm, wn, lrow, lk);
    __syncthreads();
  }
  float bias[4];
#pragma unroll
  for (int j = 0; j < 4; ++j)
    bias[j] = b2[e * DDIM + nl0 + wn * 64 + j * 16 + lrow];
#pragma unroll
  for (int i = 0; i < 2; ++i) {
#pragma unroll
    for (int r = 0; r < 4; ++r) {
      int slot = mt * 64 + wm * 32 + i * 16 + lk * 4 + r;
      int tokn = perm[slot];
      float w = wsl[slot];
#pragma unroll
      for (int j = 0; j < 4; ++j) {
        int n = nl0 + wn * 64 + j * 16 + lrow;
        float h = fmaxf(acc[i][j][r] + bias[j], 0.f);
        atomicAdd(&out[(size_t)tokn * DDIM + n], w * h);
      }
    }
  }
}

// ------- combine: 16 cols/thread --------------------------------------------
__global__ __launch_bounds__(256) void combine_kernel(const u16* __restrict__ ybuf,
                                                      const float* __restrict__ ew,
                                                      const int* __restrict__ islot,
                                                      float* __restrict__ out,
                                                      int n0, int NC, int cshift) {
  int gid = blockIdx.x * 256 + threadIdx.x;
  int t = gid >> cshift;
  int c = (gid & ((1 << cshift) - 1)) << 4;
  const int4 sl = *(const int4*)(islot + t * 4);
  const float4 w = *(const float4*)(ew + t * 4);
  float a[16];
#pragma unroll
  for (int k = 0; k < 16; ++k) a[k] = 0.f;
#define ACCROW(SL, W)                                                      \
  {                                                                        \
    u16x8 y0 = *(const u16x8*)(ybuf + (size_t)(SL)*NC + c);                \
    u16x8 y1 = *(const u16x8*)(ybuf + (size_t)(SL)*NC + c + 8);            \
    _Pragma("unroll") for (int k = 0; k < 8; ++k) {                        \
      a[k] += (W)*bf2f(y0[k]); a[8 + k] += (W)*bf2f(y1[k]);                \
    }                                                                      \
  }
  ACCROW(sl.x, w.x); ACCROW(sl.y, w.y); ACCROW(sl.z, w.z); ACCROW(sl.w, w.w);
#undef ACCROW
  float* o = out + (size_t)t * DDIM + n0 + c;
#pragma unroll
  for (int k = 0; k < 16; k += 4)
    *(float4*)(o + k) = (float4){a[k], a[k + 1], a[k + 2], a[k + 3]};
}

// ---------------------------------------------------------------------------
extern "C" void kernel_launch(void* const* d_in, const int* in_sizes, int n_in,
                              void* d_out, int out_size, void* d_ws, size_t ws_size,
                              hipStream_t stream) {
  const float* x = (const float*)d_in[0];
  const float* route_w = (const float*)d_in[1];
  const float* w1 = (const float*)d_in[2];
  const float* b1 = (const float*)d_in[3];
  const float* w2 = (const float*)d_in[4];
  const float* b2 = (const float*)d_in[5];
  float* out = (float*)d_out;

  uint8_t* ws = (uint8_t*)d_ws;
  const size_t OFF_EPACK = 0;                      // 8192 ints  = 32 KB
  const size_t OFF_EW    = 32768;                  // 32768 f    = 128 KB
  const size_t OFF_ISLOT = 163840;                 // 32768 ints = 128 KB
  const size_t OFF_TEXP  = 294912;                 // 272 ints
  const size_t OFF_PERM  = 296960;                 // 34816 ints
  const size_t OFF_WSL   = 436224;                 // 34816 f
  const size_t OFF_X     = 1048576;                // 16.78 MB bf16 x
  const size_t OFF_W1    = OFF_X + (size_t)NTOK * DDIM * 2;
  const size_t OFF_W2    = OFF_W1 + (size_t)NEXP * HDIM * DDIM * 2;
  const size_t OFF_HC    = OFF_W2 + (size_t)NEXP * DDIM * HDIM * 2;
  const size_t OFF_Y     = OFF_HC + (size_t)MAXSLOT * HDIM * 2;

  int* epack  = (int*)(ws + OFF_EPACK);
  float* ew   = (float*)(ws + OFF_EW);
  int* islot  = (int*)(ws + OFF_ISLOT);
  int* texp   = (int*)(ws + OFF_TEXP);
  int* perm   = (int*)(ws + OFF_PERM);
  float* wsl  = (float*)(ws + OFF_WSL);
  u16* xbf    = (u16*)(ws + OFF_X);
  u16* w1bf   = (u16*)(ws + OFF_W1);
  u16* w2bf   = (u16*)(ws + OFF_W2);
  u16* Hc     = (u16*)(ws + OFF_HC);
  u16* ybuf   = (u16*)(ws + OFF_Y);

  const int nba = (NEXP * HDIM * DDIM) / 2048;
  cvt2_kernel<<<dim3(nba * 2), 256, 0, stream>>>(w1, w2, w1bf, w2bf, nba);
  router_kernel<<<dim3(NTOK / 16), 256, 0, stream>>>(x, route_w, epack, ew, xbf);
  compact_kernel<<<dim3(NEXP), 1024, 0, stream>>>(epack, ew, texp, perm, wsl, islot);

  // ybuf chunk width based on available workspace (prefer 1024: single pass)
  int ybN = 0;
  for (int cand = 1024; cand >= 128; cand >>= 1) {
    if (ws_size >= OFF_Y + (size_t)MAXSLOT * cand * 2) { ybN = cand; break; }
  }

  if (ybN > 0) {
    gemm1_kernel<<<dim3(MAXMT, HDIM / 128), 256, 0, stream>>>(xbf, w1bf, b1, texp, perm, Hc, 0);
    int cshift = __builtin_ctz(ybN >> 4);
    for (int nb = 0; nb < DDIM; nb += ybN) {
      gemm2_main_kernel<<<dim3(MAXMT, ybN / 128), 256, 0, stream>>>(
          Hc, w2bf, b2, texp, ybuf, nb, ybN);
      combine_kernel<<<dim3((NTOK << cshift) / 256), 256, 0, stream>>>(
          ybuf, ew, islot, out, nb, ybN, cshift);
    }
  } else {
    long room = (long)ws_size - (long)OFF_HC;
    int CT = (int)(room / 65536);          // in 128-slot tiles
    if (CT > MAXT) CT = MAXT;
    if (CT < 16) CT = 16;
    zero_out_kernel<<<dim3((NTOK * DDIM) / 1024), 256, 0, stream>>>(out);
    for (int t0 = 0; t0 < MAXT; t0 += CT) {
      int ct = (MAXT - t0 < CT) ? (MAXT - t0) : CT;
      gemm1_kernel<<<dim3(ct * 2, HDIM / 128), 256, 0, stream>>>(
          xbf, w1bf, b1, texp, perm, Hc, t0 * 2);
      gemm2_fb_kernel<<<dim3(ct * 2, DDIM / 128), 256, 0, stream>>>(
          Hc, w2bf, b2, texp, perm, wsl, out, t0 * 2);
    }
  }
}